// Round 2
// baseline (3341.585 us; speedup 1.0000x reference)
//
#include <hip/hip_runtime.h>
#include <math.h>

// Problem constants
// D_MODEL=1024, D_INNER=2048, NHEADS=32, HEADDIM=64, CHUNK=64, B=4, L=4096
// D_IN_PROJ=4256 (z:0..2047 | xC:2048..4223 (2176) | dt:4224..4255)
// Only z (2048), first 2048 of xC, and dt (32) are needed -> N=4128 logical.
// C == ones(...) collapses the state dim: g[l] = reward[l]*sum(bw)+sum(bb),
// and the whole SSD becomes a scalar linear scan per (h,p) channel.
//
// Batches are independent -> process 4 batches sequentially through ~98 MiB
// of scratch (previous version assumed 411 MB of d_ws and faulted).

__device__ __forceinline__ float softplusf(float x) {
    return (x > 20.f) ? x : log1pf(expf(x));
}
__device__ __forceinline__ float silu_mod(float x) {  // sigmoid(x) + 0.1*x per reference
    return 1.f / (1.f + expf(-x)) + 0.1f * x;
}

// ---------------------------------------------------------------------------
// NT SGEMM: C[m,n] = sum_k A[m,k]*B[n,k] (+bias). 128x128 tile, BK=32,
// 256 threads, 8x8 micro-tile. MODE 0: in_proj with column remap + split
// store into z / xc / dtraw. MODE 1: out_proj -> out. M comes from gridDim.y.
// ---------------------------------------------------------------------------
template <int MODE, int KDIM>
__global__ __launch_bounds__(256) void sgemm_nt(
    const float* __restrict__ A, const float* __restrict__ Bm,
    const float* __restrict__ bias,
    float* __restrict__ oz, float* __restrict__ oxc, float* __restrict__ odt,
    float* __restrict__ oC)
{
    constexpr int BK = 32;
    __shared__ float As[BK][132];  // pad 132: 16B-aligned rows, 2-way reads (free)
    __shared__ float Bs[BK][132];
    const int tid = threadIdx.x;
    const int m0 = blockIdx.y * 128;
    const int n0 = blockIdx.x * 128;
    const int tm = tid & 15, tn = tid >> 4;

    float acc[8][8];
#pragma unroll
    for (int i = 0; i < 8; i++)
#pragma unroll
        for (int j = 0; j < 8; j++) acc[i][j] = 0.f;

    for (int k0 = 0; k0 < KDIM; k0 += BK) {
#pragma unroll
        for (int i = 0; i < 4; i++) {
            int f = tid + i * 256;
            int r = f >> 3, kq = f & 7;
            float4 va = *(const float4*)(A + (size_t)(m0 + r) * KDIM + k0 + kq * 4);
            As[kq * 4 + 0][r] = va.x; As[kq * 4 + 1][r] = va.y;
            As[kq * 4 + 2][r] = va.z; As[kq * 4 + 3][r] = va.w;
        }
#pragma unroll
        for (int i = 0; i < 4; i++) {
            int f = tid + i * 256;
            int r = f >> 3, kq = f & 7;
            int j = n0 + r;
            float4 vb = make_float4(0.f, 0.f, 0.f, 0.f);
            if (MODE == 0) {
                if (j < 4128) {
                    int wr = (j < 4096) ? j : j + 128;  // skip unused 128 conv cols
                    vb = *(const float4*)(Bm + (size_t)wr * KDIM + k0 + kq * 4);
                }
            } else {
                vb = *(const float4*)(Bm + (size_t)j * KDIM + k0 + kq * 4);
            }
            Bs[kq * 4 + 0][r] = vb.x; Bs[kq * 4 + 1][r] = vb.y;
            Bs[kq * 4 + 2][r] = vb.z; Bs[kq * 4 + 3][r] = vb.w;
        }
        __syncthreads();
#pragma unroll
        for (int k = 0; k < BK; k++) {
            float a[8], b[8];
            *(float4*)&a[0] = *(const float4*)&As[k][tm * 4];
            *(float4*)&a[4] = *(const float4*)&As[k][tm * 4 + 64];
            *(float4*)&b[0] = *(const float4*)&Bs[k][tn * 4];
            *(float4*)&b[4] = *(const float4*)&Bs[k][tn * 4 + 64];
#pragma unroll
            for (int i = 0; i < 8; i++)
#pragma unroll
                for (int j = 0; j < 8; j++)
                    acc[i][j] = fmaf(a[i], b[j], acc[i][j]);
        }
        __syncthreads();
    }

#pragma unroll
    for (int jb = 0; jb < 2; jb++) {
        int jn = n0 + tn * 4 + jb * 64;
        if (MODE == 0 && jn >= 4128) continue;
        float4 bs4 = make_float4(0.f, 0.f, 0.f, 0.f);
        if (MODE == 0) {
            int wr = (jn < 4096) ? jn : jn + 128;
            bs4 = *(const float4*)(bias + wr);
        }
#pragma unroll
        for (int i = 0; i < 8; i++) {
            int rm = m0 + tm * 4 + (i & 3) + (i >> 2) * 64;
            float4 v;
            v.x = acc[i][jb * 4 + 0] + bs4.x;
            v.y = acc[i][jb * 4 + 1] + bs4.y;
            v.z = acc[i][jb * 4 + 2] + bs4.z;
            v.w = acc[i][jb * 4 + 3] + bs4.w;
            if (MODE == 0) {
                if (jn < 2048)      *(float4*)(oz  + (size_t)rm * 2048 + jn) = v;
                else if (jn < 4096) *(float4*)(oxc + (size_t)rm * 2048 + jn - 2048) = v;
                else                *(float4*)(odt + (size_t)rm * 32 + jn - 4096) = v;
            } else {
                *(float4*)(oC + (size_t)rm * 1024 + jn) = v;
            }
        }
    }
}

// ---------------------------------------------------------------------------
// scanA: one batch. Per (h, chunk) block, 64 threads (p).
// Fuses: depthwise conv(4) + silu' + softplus(dt) + decay cumsum + 64-step
// local scan  y[l] = y[l-1]*exp(a_l) + g_l * (x_conv*dt).
// Emits ylocal (4096,2048), decay=exp(cumA) (4096,32), chunk summaries E,F.
// ---------------------------------------------------------------------------
__global__ __launch_bounds__(64) void scanA(
    const float* __restrict__ xc, const float* __restrict__ dtraw,
    const float* __restrict__ reward,
    const float* __restrict__ conv_w, const float* __restrict__ conv_b,
    const float* __restrict__ dt_bias, const float* __restrict__ A_log,
    const float* __restrict__ bw, const float* __restrict__ bb,
    float* __restrict__ ylocal, float* __restrict__ decay,
    float* __restrict__ Fb, float* __restrict__ Eb)
{
    const int blk = blockIdx.x;        // h*64 + t
    const int t = blk & 63;
    const int h = blk >> 6;            // 0..31
    const int p = threadIdx.x;         // 0..63
    const int l0 = t * 64;

    __shared__ float xs[67][65];       // conv input tile + 3-halo, padded
    __shared__ float gbuf[64], ebuf[64], dtbuf[64];
    __shared__ float cum63;

    // g[l] = reward*sum(bw) + sum(bb)  (C == ones collapses the n dim)
    float v1 = bw[p] + bw[p + 64];
    float v2 = bb[p] + bb[p + 64];
#pragma unroll
    for (int o = 32; o > 0; o >>= 1) {
        v1 += __shfl_down(v1, o, 64);
        v2 += __shfl_down(v2, o, 64);
    }
    const float sbw = __shfl(v1, 0, 64);
    const float sbb = __shfl(v2, 0, 64);

    const int l = l0 + p;
    const float dt = softplusf(dtraw[(size_t)l * 32 + h] + dt_bias[h]);
    const float a = -expf(A_log[h]) * dt;
    float cum = a;
#pragma unroll
    for (int o = 1; o < 64; o <<= 1) {   // inclusive scan across the wave
        float uo = __shfl_up(cum, o, 64);
        if (p >= o) cum += uo;
    }
    decay[(size_t)l * 32 + h] = expf(cum);
    gbuf[p] = reward[l] * sbw + sbb;
    ebuf[p] = expf(a);
    dtbuf[p] = dt;
    if (p == 63) cum63 = cum;

    const int c = h * 64 + p;
    for (int r = 0; r < 67; r++) {
        int ls = l0 - 3 + r;
        xs[r][p] = (ls >= 0) ? xc[(size_t)ls * 2048 + c] : 0.f;
    }
    __syncthreads();

    const float w0 = conv_w[c * 4 + 0], w1 = conv_w[c * 4 + 1],
                w2 = conv_w[c * 4 + 2], w3 = conv_w[c * 4 + 3];
    const float cb = conv_b[c];
    float y = 0.f;
    float* outp = ylocal + (size_t)l0 * 2048 + c;
#pragma unroll 4
    for (int i = 0; i < 64; i++) {
        float v = cb + xs[i][p] * w0 + xs[i + 1][p] * w1 +
                  xs[i + 2][p] * w2 + xs[i + 3][p] * w3;
        float xdt = silu_mod(v) * dtbuf[i];
        y = y * ebuf[i] + gbuf[i] * xdt;
        outp[(size_t)i * 2048] = y;
    }
    Fb[((size_t)h * 64 + t) * 64 + p] = y;
    if (p == 0) Eb[(size_t)h * 64 + t] = expf(cum63);
}

// ---------------------------------------------------------------------------
// scanB: one batch. Cross-chunk scan, one thread per (h,p) channel, 64 steps.
// Sprev[h,t,p] = state entering chunk t.
// ---------------------------------------------------------------------------
__global__ void scanB(const float* __restrict__ Fb, const float* __restrict__ Eb,
                      float* __restrict__ Sprev)
{
    int idx = blockIdx.x * blockDim.x + threadIdx.x;  // 2048
    int p = idx & 63;
    int h = idx >> 6;
    int base = h * 64;
    float S = 0.f;
    for (int t = 0; t < 64; t++) {
        Sprev[(size_t)(base + t) * 64 + p] = S;
        S = S * Eb[base + t] + Fb[(size_t)(base + t) * 64 + p];
    }
}

// ---------------------------------------------------------------------------
// passC: one batch. y = (y_local + S_in * exp(cumA)) * (sigmoid(z)+0.1z).
// ---------------------------------------------------------------------------
__global__ __launch_bounds__(256) void passC(
    float* __restrict__ y, const float* __restrict__ z,
    const float* __restrict__ Sprev, const float* __restrict__ decay)
{
    int i4 = blockIdx.x * blockDim.x + threadIdx.x;
    size_t idx = (size_t)i4 * 4;
    int row = (int)(idx >> 11);        // l in [0,4096)
    int cc = (int)(idx & 2047);
    int t = row >> 6;
    int h = cc >> 6, p = cc & 63;
    float4 yv = *(float4*)(y + idx);
    float4 sv = *(const float4*)(Sprev + ((size_t)(h * 64 + t)) * 64 + p);
    float d = decay[(size_t)row * 32 + h];
    float4 zv = *(const float4*)(z + idx);
    float4 o;
    o.x = (yv.x + sv.x * d) * silu_mod(zv.x);
    o.y = (yv.y + sv.y * d) * silu_mod(zv.y);
    o.z = (yv.z + sv.z * d) * silu_mod(zv.z);
    o.w = (yv.w + sv.w * d) * silu_mod(zv.w);
    *(float4*)(y + idx) = o;
}

// ---------------------------------------------------------------------------
extern "C" void kernel_launch(void* const* d_in, const int* in_sizes, int n_in,
                              void* d_out, int out_size, void* d_ws, size_t ws_size,
                              hipStream_t stream)
{
    const float* u       = (const float*)d_in[0];
    const float* reward  = (const float*)d_in[1];
    const float* in_w    = (const float*)d_in[2];
    const float* in_b    = (const float*)d_in[3];
    const float* conv_w  = (const float*)d_in[4];
    const float* conv_b  = (const float*)d_in[5];
    const float* bw      = (const float*)d_in[6];
    const float* bb      = (const float*)d_in[7];
    const float* dt_bias = (const float*)d_in[8];
    const float* A_log   = (const float*)d_in[9];
    const float* out_w   = (const float*)d_in[10];
    float* out = (float*)d_out;

    // Per-batch scratch (~98 MiB), reused across the 4 batches.
    float* ws = (float*)d_ws;
    size_t off = 0;
    float* z      = ws + off; off += (size_t)4096 * 2048;   // 32 MiB
    float* xc     = ws + off; off += (size_t)4096 * 2048;   // 32 MiB
    float* ylocal = ws + off; off += (size_t)4096 * 2048;   // 32 MiB
    float* dtraw  = ws + off; off += (size_t)4096 * 32;
    float* decay  = ws + off; off += (size_t)4096 * 32;
    float* Fb     = ws + off; off += (size_t)32 * 64 * 64;
    float* Eb     = ws + off; off += (size_t)32 * 64;
    float* Sprev  = ws + off; off += (size_t)32 * 64 * 64;

    for (int b = 0; b < 4; b++) {
        const float* ub = u + (size_t)b * 4096 * 1024;
        const float* rb = reward + (size_t)b * 4096;
        float* ob = out + (size_t)b * 4096 * 1024;

        // 1) in_proj GEMM (N=4128 logical, 33 col-blocks; M=4096)
        sgemm_nt<0, 1024><<<dim3(33, 32), 256, 0, stream>>>(
            ub, in_w, in_b, z, xc, dtraw, nullptr);
        // 2) conv + local chunk scan
        scanA<<<2048, 64, 0, stream>>>(xc, dtraw, rb, conv_w, conv_b,
                                       dt_bias, A_log, bw, bb,
                                       ylocal, decay, Fb, Eb);
        // 3) cross-chunk scan
        scanB<<<8, 256, 0, stream>>>(Fb, Eb, Sprev);
        // 4) add carried state + z-gating (in place on ylocal)
        passC<<<8192, 256, 0, stream>>>(ylocal, z, Sprev, decay);
        // 5) out_proj GEMM (M=4096, N=1024)
        sgemm_nt<1, 2048><<<dim3(8, 32), 256, 0, stream>>>(
            ylocal, out_w, nullptr, nullptr, nullptr, nullptr, ob);
    }
}

// Round 3
// 1545.467 us; speedup vs baseline: 2.1622x; 2.1622x over previous
//
#include <hip/hip_runtime.h>
#include <hip/hip_bf16.h>
#include <math.h>

// D_MODEL=1024, D_INNER=2048, NHEADS=32, HEADDIM=64, CHUNK=64, B=4, L=4096
// C == ones collapses the state dim -> scalar scan per (h,p) channel.
// GEMMs run as bf16x3 split MFMA (Ah*Bh + Ah*Bl + Al*Bh), fp32-equivalent
// precision (~2^-17 rel), on the 2.4 PF bf16 matrix pipe.
//
// Workspace regions (total 98.01 MiB == round-2-certified footprint):
//  R0 32MiB: zh/zl        [gemm1 -> passC]
//  R1 32MiB: xch/xcl      [gemm1 -> scanA]  then yh/yl [passC -> gemm2]
//  R2 32MiB: w1h/w1l(16.5)[split -> gemm1] -> ylh/yll(32) [scanA -> passC]
//            -> w2h/w2l(8)[split -> gemm2]   (cycled per batch)

typedef __attribute__((ext_vector_type(8))) short bf16x8;
typedef __attribute__((ext_vector_type(4))) float f32x4;

__device__ __forceinline__ float bf2f(unsigned short u) {
    union { float f; unsigned int i; } x; x.i = ((unsigned int)u) << 16; return x.f;
}
__device__ __forceinline__ unsigned short f2bf(float f) {  // RNE
    union { float f; unsigned int i; } x; x.f = f;
    unsigned int r = x.i + 0x7fffu + ((x.i >> 16) & 1u);
    return (unsigned short)(r >> 16);
}
__device__ __forceinline__ float softplusf(float x) {
    return (x > 20.f) ? x : log1pf(expf(x));
}
__device__ __forceinline__ float silu_mod(float x) {  // sigmoid(x)+0.1x per ref
    return 1.f / (1.f + expf(-x)) + 0.1f * x;
}

#define GLOAD_LDS16(gp, lp)                                                   \
    __builtin_amdgcn_global_load_lds(                                         \
        (const __attribute__((address_space(1))) void*)(gp),                  \
        (__attribute__((address_space(3))) void*)(lp), 16, 0, 0)

// packed split: (x,y) -> hi pair (packed 2xbf16 in uint) + lo pair
__device__ __forceinline__ void cvt_split2(float x, float y,
                                           unsigned int* hi, unsigned int* lo) {
    __hip_bfloat162 h2 = __float22bfloat162_rn(make_float2(x, y));
    unsigned int h; __builtin_memcpy(&h, &h2, 4);
    union { float f; unsigned int i; } fx, fy;
    fx.i = h << 16;            // low bf16 as f32
    fy.i = h & 0xffff0000u;    // high bf16 as f32
    __hip_bfloat162 l2 = __float22bfloat162_rn(make_float2(x - fx.f, y - fy.f));
    unsigned int l; __builtin_memcpy(&l, &l2, 4);
    *hi = h; *lo = l;
}

// ---------------------------------------------------------------------------
// bf16x3 MFMA NT-GEMM, 128x128 tile, BK=32, 256 thr = 4 waves (2x2), each wave
// 4x4 tiles of 16x16x32.  MODE 0: in_proj — A fp32 (split in-register),
// split-store z/xc + dtraw.  MODE 1: out_proj — A pre-split bf16, fp32 out.
// ---------------------------------------------------------------------------
template <int MODE, int KDIM>
__global__ __launch_bounds__(256) void mfma_gemm(
    const float* __restrict__ Af,
    const unsigned short* __restrict__ Abh, const unsigned short* __restrict__ Abl,
    const unsigned short* __restrict__ Bh, const unsigned short* __restrict__ Bl,
    const float* __restrict__ bias,
    unsigned short* __restrict__ zh, unsigned short* __restrict__ zl,
    unsigned short* __restrict__ xch, unsigned short* __restrict__ xcl,
    float* __restrict__ dtraw, float* __restrict__ outC)
{
    __shared__ __align__(16) char smem[32768];
    float* Asf = (float*)smem;                           // MODE 0: 16 KB fp32 A
    unsigned short* Ash = (unsigned short*)smem;         // MODE 1: 8 KB
    unsigned short* Asl = (unsigned short*)(smem + 8192);
    unsigned short* Bsh = (unsigned short*)(smem + 16384);
    unsigned short* Bsl = (unsigned short*)(smem + 24576);

    const int tid = threadIdx.x;
    const int lane = tid & 63, w = tid >> 6;
    const int wm = w & 1, wn = w >> 1;
    const int m0 = blockIdx.y * 128, n0 = blockIdx.x * 128;

    // staging addresses
    // B (bf16): 8 segs of 1KB (16 rows x 32 bf16); wave w handles segs 2w,2w+1
    const size_t offB0 = (size_t)(n0 + (2 * w) * 16 + (lane >> 2)) * KDIM + (lane & 3) * 8;
    const size_t offB1 = offB0 + (size_t)16 * KDIM;
    const int ldsB0 = (2 * w) * 512, ldsB1 = (2 * w + 1) * 512;
    // MODE0 A (fp32): 16 segs of 1KB (8 rows x 32 f32); wave w segs 4w..4w+3
    size_t offAf[4];
    int ldsAf[4];
    size_t offA0 = 0, offA1 = 0;
    int ldsA0 = 0, ldsA1 = 0;
    if (MODE == 0) {
#pragma unroll
        for (int i = 0; i < 4; i++) {
            int seg = 4 * w + i;
            offAf[i] = (size_t)(m0 + seg * 8 + (lane >> 3)) * KDIM + (lane & 7) * 4;
            ldsAf[i] = seg * 256;  // float elements
        }
    } else {
        offA0 = (size_t)(m0 + (2 * w) * 16 + (lane >> 2)) * KDIM + (lane & 3) * 8;
        offA1 = offA0 + (size_t)16 * KDIM;
        ldsA0 = (2 * w) * 512; ldsA1 = (2 * w + 1) * 512;
    }

    f32x4 acc[4][4];
#pragma unroll
    for (int i = 0; i < 4; i++)
#pragma unroll
        for (int j = 0; j < 4; j++) acc[i][j] = (f32x4){0.f, 0.f, 0.f, 0.f};

    const int fr = lane & 15, q = lane >> 4;

    for (int k0 = 0; k0 < KDIM; k0 += 32) {
        __syncthreads();
        if (MODE == 0) {
#pragma unroll
            for (int i = 0; i < 4; i++)
                GLOAD_LDS16(Af + offAf[i] + k0, Asf + ldsAf[i]);
        } else {
            GLOAD_LDS16(Abh + offA0 + k0, Ash + ldsA0);
            GLOAD_LDS16(Abh + offA1 + k0, Ash + ldsA1);
            GLOAD_LDS16(Abl + offA0 + k0, Asl + ldsA0);
            GLOAD_LDS16(Abl + offA1 + k0, Asl + ldsA1);
        }
        GLOAD_LDS16(Bh + offB0 + k0, Bsh + ldsB0);
        GLOAD_LDS16(Bh + offB1 + k0, Bsh + ldsB1);
        GLOAD_LDS16(Bl + offB0 + k0, Bsl + ldsB0);
        GLOAD_LDS16(Bl + offB1 + k0, Bsl + ldsB1);
        __syncthreads();

        bf16x8 a_h[4], a_l[4], b_h[4], b_l[4];
#pragma unroll
        for (int nt = 0; nt < 4; nt++) {
            int r = (wn * 64 + nt * 16 + fr) * 32 + q * 8;
            b_h[nt] = *(const bf16x8*)&Bsh[r];
            b_l[nt] = *(const bf16x8*)&Bsl[r];
        }
#pragma unroll
        for (int mt = 0; mt < 4; mt++) {
            if (MODE == 0) {
                const float* ap = &Asf[(wm * 64 + mt * 16 + fr) * 32 + q * 8];
                float4 a0 = *(const float4*)ap;
                float4 a1 = *(const float4*)(ap + 4);
                union { bf16x8 v; unsigned int u[4]; } H, L;
                cvt_split2(a0.x, a0.y, &H.u[0], &L.u[0]);
                cvt_split2(a0.z, a0.w, &H.u[1], &L.u[1]);
                cvt_split2(a1.x, a1.y, &H.u[2], &L.u[2]);
                cvt_split2(a1.z, a1.w, &H.u[3], &L.u[3]);
                a_h[mt] = H.v; a_l[mt] = L.v;
            } else {
                int r = (wm * 64 + mt * 16 + fr) * 32 + q * 8;
                a_h[mt] = *(const bf16x8*)&Ash[r];
                a_l[mt] = *(const bf16x8*)&Asl[r];
            }
        }
#pragma unroll
        for (int mt = 0; mt < 4; mt++)
#pragma unroll
            for (int nt = 0; nt < 4; nt++) {
                acc[mt][nt] = __builtin_amdgcn_mfma_f32_16x16x32_bf16(
                    a_h[mt], b_h[nt], acc[mt][nt], 0, 0, 0);
                acc[mt][nt] = __builtin_amdgcn_mfma_f32_16x16x32_bf16(
                    a_h[mt], b_l[nt], acc[mt][nt], 0, 0, 0);
                acc[mt][nt] = __builtin_amdgcn_mfma_f32_16x16x32_bf16(
                    a_l[mt], b_h[nt], acc[mt][nt], 0, 0, 0);
            }
    }

    // epilogue: D[row=q*4+reg][col=lane&15] per 16x16 tile (m89-verified map)
#pragma unroll
    for (int nt = 0; nt < 4; nt++) {
        int jn = n0 + wn * 64 + nt * 16 + fr;
        if (MODE == 0 && jn >= 4128) continue;
        float bv = 0.f;
        if (MODE == 0) bv = bias[jn < 4096 ? jn : jn + 128];
#pragma unroll
        for (int mt = 0; mt < 4; mt++) {
#pragma unroll
            for (int reg = 0; reg < 4; reg++) {
                int rm = m0 + wm * 64 + mt * 16 + q * 4 + reg;
                float v = acc[mt][nt][reg] + bv;
                if (MODE == 0) {
                    if (jn < 2048) {
                        size_t o = (size_t)rm * 2048 + jn;
                        unsigned short h = f2bf(v);
                        zh[o] = h; zl[o] = f2bf(v - bf2f(h));
                    } else if (jn < 4096) {
                        size_t o = (size_t)rm * 2048 + (jn - 2048);
                        unsigned short h = f2bf(v);
                        xch[o] = h; xcl[o] = f2bf(v - bf2f(h));
                    } else {
                        dtraw[(size_t)rm * 32 + (jn - 4096)] = v;
                    }
                } else {
                    outC[(size_t)rm * 1024 + jn] = v;
                }
            }
        }
    }
}

// ---------------------------------------------------------------------------
// weight splitters. MODE 0: straight (rows x 1024*?cols handled as flat f4).
// MODE 1: in_w remap: row<4096 -> row; 4096..4127 -> row+128 (dt); else zero.
// ---------------------------------------------------------------------------
__global__ __launch_bounds__(256) void split_w1(
    const float* __restrict__ src, unsigned short* __restrict__ h,
    unsigned short* __restrict__ l)
{
    int i = blockIdx.x * 256 + threadIdx.x;   // 4224*256 threads
    int row = i >> 8, c4 = (i & 255) * 4;
    int sr = (row < 4096) ? row : (row < 4128 ? row + 128 : -1);
    float4 v = make_float4(0.f, 0.f, 0.f, 0.f);
    if (sr >= 0) v = *(const float4*)(src + (size_t)sr * 1024 + c4);
    ushort4 hv, lv;
    unsigned short t;
    t = f2bf(v.x); hv.x = t; lv.x = f2bf(v.x - bf2f(t));
    t = f2bf(v.y); hv.y = t; lv.y = f2bf(v.y - bf2f(t));
    t = f2bf(v.z); hv.z = t; lv.z = f2bf(v.z - bf2f(t));
    t = f2bf(v.w); hv.w = t; lv.w = f2bf(v.w - bf2f(t));
    size_t o = (size_t)row * 1024 + c4;
    *(ushort4*)(h + o) = hv;
    *(ushort4*)(l + o) = lv;
}

__global__ __launch_bounds__(256) void split_flat(
    const float* __restrict__ src, unsigned short* __restrict__ h,
    unsigned short* __restrict__ l)
{
    size_t o = ((size_t)blockIdx.x * 256 + threadIdx.x) * 4;
    float4 v = *(const float4*)(src + o);
    ushort4 hv, lv;
    unsigned short t;
    t = f2bf(v.x); hv.x = t; lv.x = f2bf(v.x - bf2f(t));
    t = f2bf(v.y); hv.y = t; lv.y = f2bf(v.y - bf2f(t));
    t = f2bf(v.z); hv.z = t; lv.z = f2bf(v.z - bf2f(t));
    t = f2bf(v.w); hv.w = t; lv.w = f2bf(v.w - bf2f(t));
    *(ushort4*)(h + o) = hv;
    *(ushort4*)(l + o) = lv;
}

// ---------------------------------------------------------------------------
// scanA: one batch. Per (h, chunk) block, 64 threads (p). conv4 + silu' +
// softplus(dt) + decay cumsum + 64-step local scan. xc/ylocal are split bf16.
// ---------------------------------------------------------------------------
__global__ __launch_bounds__(64) void scanA(
    const unsigned short* __restrict__ xch, const unsigned short* __restrict__ xcl,
    const float* __restrict__ dtraw, const float* __restrict__ reward,
    const float* __restrict__ conv_w, const float* __restrict__ conv_b,
    const float* __restrict__ dt_bias, const float* __restrict__ A_log,
    const float* __restrict__ bw, const float* __restrict__ bb,
    unsigned short* __restrict__ ylh, unsigned short* __restrict__ yll,
    float* __restrict__ decay, float* __restrict__ Fb, float* __restrict__ Eb)
{
    const int blk = blockIdx.x;        // h*64 + t
    const int t = blk & 63;
    const int h = blk >> 6;
    const int p = threadIdx.x;
    const int l0 = t * 64;

    __shared__ float xs[67][65];
    __shared__ float gbuf[64], ebuf[64], dtbuf[64];
    __shared__ float cum63;

    float v1 = bw[p] + bw[p + 64];
    float v2 = bb[p] + bb[p + 64];
#pragma unroll
    for (int o = 32; o > 0; o >>= 1) {
        v1 += __shfl_down(v1, o, 64);
        v2 += __shfl_down(v2, o, 64);
    }
    const float sbw = __shfl(v1, 0, 64);
    const float sbb = __shfl(v2, 0, 64);

    const int l = l0 + p;
    const float dt = softplusf(dtraw[(size_t)l * 32 + h] + dt_bias[h]);
    const float a = -expf(A_log[h]) * dt;
    float cum = a;
#pragma unroll
    for (int o = 1; o < 64; o <<= 1) {
        float uo = __shfl_up(cum, o, 64);
        if (p >= o) cum += uo;
    }
    decay[(size_t)l * 32 + h] = expf(cum);
    gbuf[p] = reward[l] * sbw + sbb;
    ebuf[p] = expf(a);
    dtbuf[p] = dt;
    if (p == 63) cum63 = cum;

    const int c = h * 64 + p;
    for (int r = 0; r < 67; r++) {
        int ls = l0 - 3 + r;
        float x = 0.f;
        if (ls >= 0) {
            size_t o = (size_t)ls * 2048 + c;
            x = bf2f(xch[o]) + bf2f(xcl[o]);
        }
        xs[r][p] = x;
    }
    __syncthreads();

    const float w0 = conv_w[c * 4 + 0], w1 = conv_w[c * 4 + 1],
                w2 = conv_w[c * 4 + 2], w3 = conv_w[c * 4 + 3];
    const float cb = conv_b[c];
    float y = 0.f;
    size_t outp = (size_t)l0 * 2048 + c;
#pragma unroll 4
    for (int i = 0; i < 64; i++) {
        float v = cb + xs[i][p] * w0 + xs[i + 1][p] * w1 +
                  xs[i + 2][p] * w2 + xs[i + 3][p] * w3;
        float xdt = silu_mod(v) * dtbuf[i];
        y = y * ebuf[i] + gbuf[i] * xdt;
        unsigned short hh = f2bf(y);
        ylh[outp] = hh;
        yll[outp] = f2bf(y - bf2f(hh));
        outp += 2048;
    }
    Fb[((size_t)h * 64 + t) * 64 + p] = y;
    if (p == 0) Eb[(size_t)h * 64 + t] = expf(cum63);
}

// ---------------------------------------------------------------------------
__global__ void scanB(const float* __restrict__ Fb, const float* __restrict__ Eb,
                      float* __restrict__ Sprev)
{
    int idx = blockIdx.x * blockDim.x + threadIdx.x;  // 2048
    int p = idx & 63;
    int h = idx >> 6;
    int base = h * 64;
    float S = 0.f;
    for (int t = 0; t < 64; t++) {
        Sprev[(size_t)(base + t) * 64 + p] = S;
        S = S * Eb[base + t] + Fb[(size_t)(base + t) * 64 + p];
    }
}

// ---------------------------------------------------------------------------
// passC: y = (ylocal + S*decay) * silu_mod(z), emitted pre-split for gemm2.
// ---------------------------------------------------------------------------
__global__ __launch_bounds__(256) void passC(
    const unsigned short* __restrict__ ylh, const unsigned short* __restrict__ yll,
    const unsigned short* __restrict__ zh, const unsigned short* __restrict__ zl,
    const float* __restrict__ Sprev, const float* __restrict__ decay,
    unsigned short* __restrict__ yh, unsigned short* __restrict__ yl)
{
    size_t idx = ((size_t)blockIdx.x * 256 + threadIdx.x) * 4;
    int row = (int)(idx >> 11);
    int cc = (int)(idx & 2047);
    int t = row >> 6;
    int h = cc >> 6, p = cc & 63;
    ushort4 ah = *(const ushort4*)(ylh + idx);
    ushort4 al = *(const ushort4*)(yll + idx);
    ushort4 bh = *(const ushort4*)(zh + idx);
    ushort4 bl = *(const ushort4*)(zl + idx);
    float4 sv = *(const float4*)(Sprev + ((size_t)(h * 64 + t)) * 64 + p);
    float d = decay[(size_t)row * 32 + h];
    float y0 = (bf2f(ah.x) + bf2f(al.x) + sv.x * d) * silu_mod(bf2f(bh.x) + bf2f(bl.x));
    float y1 = (bf2f(ah.y) + bf2f(al.y) + sv.y * d) * silu_mod(bf2f(bh.y) + bf2f(bl.y));
    float y2 = (bf2f(ah.z) + bf2f(al.z) + sv.z * d) * silu_mod(bf2f(bh.z) + bf2f(bl.z));
    float y3 = (bf2f(ah.w) + bf2f(al.w) + sv.w * d) * silu_mod(bf2f(bh.w) + bf2f(bl.w));
    ushort4 hv, lv;
    unsigned short tbf;
    tbf = f2bf(y0); hv.x = tbf; lv.x = f2bf(y0 - bf2f(tbf));
    tbf = f2bf(y1); hv.y = tbf; lv.y = f2bf(y1 - bf2f(tbf));
    tbf = f2bf(y2); hv.z = tbf; lv.z = f2bf(y2 - bf2f(tbf));
    tbf = f2bf(y3); hv.w = tbf; lv.w = f2bf(y3 - bf2f(tbf));
    *(ushort4*)(yh + idx) = hv;
    *(ushort4*)(yl + idx) = lv;
}

// ---------------------------------------------------------------------------
extern "C" void kernel_launch(void* const* d_in, const int* in_sizes, int n_in,
                              void* d_out, int out_size, void* d_ws, size_t ws_size,
                              hipStream_t stream)
{
    const float* u       = (const float*)d_in[0];
    const float* reward  = (const float*)d_in[1];
    const float* in_w    = (const float*)d_in[2];
    const float* in_b    = (const float*)d_in[3];
    const float* conv_w  = (const float*)d_in[4];
    const float* conv_b  = (const float*)d_in[5];
    const float* bw      = (const float*)d_in[6];
    const float* bb      = (const float*)d_in[7];
    const float* dt_bias = (const float*)d_in[8];
    const float* A_log   = (const float*)d_in[9];
    const float* out_w   = (const float*)d_in[10];
    float* out = (float*)d_out;

    char* p = (char*)d_ws;
    const size_t MB32 = (size_t)4096 * 2048 * 2 * 2;  // 33,554,432 B
    unsigned short* zh  = (unsigned short*)p;                    // R0
    unsigned short* zl  = zh + (size_t)4096 * 2048;
    unsigned short* xch = (unsigned short*)(p + MB32);           // R1
    unsigned short* xcl = xch + (size_t)4096 * 2048;
    char* R2 = p + 2 * MB32;                                     // R2
    unsigned short* w1h = (unsigned short*)R2;
    unsigned short* w1l = w1h + (size_t)4224 * 1024;
    unsigned short* ylh = (unsigned short*)R2;
    unsigned short* yll = ylh + (size_t)4096 * 2048;
    unsigned short* w2h = (unsigned short*)R2;
    unsigned short* w2l = w2h + (size_t)1024 * 2048;
    char* ps = p + 3 * MB32;
    float* dtraw = (float*)ps;                 ps += (size_t)4096 * 32 * 4;
    float* decay = (float*)ps;                 ps += (size_t)4096 * 32 * 4;
    float* Fb    = (float*)ps;                 ps += (size_t)32 * 64 * 64 * 4;
    float* Eb    = (float*)ps;                 ps += (size_t)32 * 64 * 4;
    float* Sprev = (float*)ps;                 ps += (size_t)32 * 64 * 64 * 4;
    unsigned short* yh = xch;  // passC output reuses R1
    unsigned short* yl = xcl;

    for (int b = 0; b < 4; b++) {
        const float* ub = u + (size_t)b * 4096 * 1024;
        const float* rb = reward + (size_t)b * 4096;
        float* ob = out + (size_t)b * 4096 * 1024;

        // w1 split into R2 (re-done per batch; R2 is recycled below)
        split_w1<<<4224, 256, 0, stream>>>(in_w, w1h, w1l);
        // 1) in_proj: A=u fp32 (in-register split), B=w1 split bf16
        mfma_gemm<0, 1024><<<dim3(33, 32), 256, 0, stream>>>(
            ub, nullptr, nullptr, w1h, w1l, in_b,
            zh, zl, xch, xcl, dtraw, nullptr);
        // 2) conv + local chunk scan (xc -> ylocal, both split bf16)
        scanA<<<2048, 64, 0, stream>>>(xch, xcl, dtraw, rb, conv_w, conv_b,
                                       dt_bias, A_log, bw, bb,
                                       ylh, yll, decay, Fb, Eb);
        // 3) cross-chunk scan
        scanB<<<8, 256, 0, stream>>>(Fb, Eb, Sprev);
        // 4) gate + carried state -> y split (into R1)
        passC<<<8192, 256, 0, stream>>>(ylh, yll, zh, zl, Sprev, decay, yh, yl);
        // w2 split into R2 (ylocal dead after passC)
        split_flat<<<2048, 256, 0, stream>>>(out_w, w2h, w2l);
        // 5) out_proj: A=y split bf16, B=w2 split bf16 -> fp32 out
        mfma_gemm<1, 2048><<<dim3(8, 32), 256, 0, stream>>>(
            nullptr, yh, yl, w2h, w2l, nullptr,
            nullptr, nullptr, nullptr, nullptr, nullptr, ob);
    }
}